// Round 12
// baseline (1134.212 us; speedup 1.0000x reference)
//
#include <hip/hip_runtime.h>
#include <hip/hip_bf16.h>

#define BATCH 16
#define CH 256
#define HH 128
#define WW 128
#define HWSZ (HH * WW)
#define NHEAD 8
#define DHEAD 32
#define PW 132       // padded spatial width  (2 halo each side)
#define PPIX (132 * 132)
#define ROWS 264     // LDS row stride in shorts
#define NBLK 512     // persistent blocks (2 per CU)
#define NITP 24      // proj tiles per block  (12288 / 512)
#define NITF 8       // fcln tiles per block  (4096 / 512)

typedef __attribute__((ext_vector_type(8))) short bf16x8;
typedef __attribute__((ext_vector_type(4))) float f32x4;
typedef _Float16 h2v __attribute__((ext_vector_type(2)));

__device__ __forceinline__ unsigned short f2h(float f) {
    _Float16 h = (_Float16)f;
    return __builtin_bit_cast(unsigned short, h);
}
// packed f32x2 -> bf16x2 in one u32 (v_cvt_pk_bf16_f32 on gfx950)
__device__ __forceinline__ unsigned pkbf(float a, float b) {
    __hip_bfloat162_raw r = __hip_bfloat162_raw(__float22bfloat162_rn(make_float2(a, b)));
    return (unsigned)r.x | ((unsigned)r.y << 16);
}

#if __has_builtin(__builtin_amdgcn_fdot2)
#define DOT2(a, b, c) __builtin_amdgcn_fdot2((a), (b), (c), false)
#else
#define DOT2(a, b, c) ((c) + (float)(a)[0] * (float)(b)[0] + (float)(a)[1] * (float)(b)[1])
#endif

// ---------------------------------------------------------------------------
// Kernel Z: zero the spatial border of padded K/V buffers (1040 px per b,h).
// ---------------------------------------------------------------------------
__global__ __launch_bounds__(256)
void zpad_kernel(unsigned short* __restrict__ kpad, unsigned short* __restrict__ vpad)
{
    int bid = blockIdx.x;  // 0..255 : (bh, tensor)
    unsigned short* dst = ((bid & 1) ? vpad : kpad) + (size_t)(bid >> 1) * PPIX * DHEAD;
    const uint4 z = {0u, 0u, 0u, 0u};
    for (int i = threadIdx.x; i < 1040; i += 256) {
        int row, col;
        if (i < 264)      { row = i / 132; col = i - row * 132; }
        else if (i < 528) { int j = i - 264; int r = j / 132; row = 130 + r; col = j - r * 132; }
        else              { int j = i - 528; row = 2 + (j >> 2); int c = j & 3; col = (c < 2) ? c : (128 + c); }
        uint4* p = reinterpret_cast<uint4*>(dst + (size_t)(row * PW + col) * DHEAD);
        p[0] = z; p[1] = z; p[2] = z; p[3] = z;
    }
}

// ---------------------------------------------------------------------------
// Kernel 0: convert wq|wk|wv|wfc fp32 -> bf16, stashed in d_ws tail.
// ---------------------------------------------------------------------------
__global__ __launch_bounds__(256)
void prep_kernel(const float* __restrict__ wq, const float* __restrict__ wk,
                 const float* __restrict__ wv, const float* __restrict__ wfc,
                 unsigned short* __restrict__ wb)
{
    const float* src = (blockIdx.y == 0) ? wq : (blockIdx.y == 1) ? wk
                     : (blockIdx.y == 2) ? wv : wfc;
    unsigned short* dst = wb + blockIdx.y * 65536;
    int e = (blockIdx.x * 256 + threadIdx.x) * 8;
    const float4* s = reinterpret_cast<const float4*>(src + e);
    float4 a = s[0], c = s[1];
    uint4 u;
    u.x = pkbf(a.x, a.y); u.y = pkbf(a.z, a.w);
    u.z = pkbf(c.x, c.y); u.w = pkbf(c.z, c.w);
    *reinterpret_cast<uint4*>(dst + e) = u;
}

// ---------------------------------------------------------------------------
// Kernel 1: projections, PERSISTENT: each block walks NITP consecutive tiles
// with cross-tile double-buffered LDS. Loads for tile i+1 fly during
// compute+store of tile i -> continuous HBM pressure.
// ---------------------------------------------------------------------------
__global__ __launch_bounds__(512, 4)
void proj_kernel(const float* __restrict__ q, const float* __restrict__ k,
                 const float* __restrict__ v, const unsigned short* __restrict__ wb,
                 unsigned short* __restrict__ qh, unsigned short* __restrict__ kpad,
                 unsigned short* __restrict__ vpad)
{
    __shared__ __align__(16) unsigned short lB[2][64 * ROWS];  // 67.6 KB

    const int t = threadIdx.x;
    const int lane = t & 63;
    const int wid  = t >> 6;   // 0..7 : 32-out-ch slab / staging ch group
    const int lrow = lane & 15;
    const int lkg  = lane >> 4;
    const int pB   = t & 63;
    const int cg   = t >> 6;
    const int psw  = pB >> 3;

    const int gbase = blockIdx.x * NITP;

    // tile -> source helpers (uniform / scalar per block)
    auto xptr = [&](int g) -> const float* {
        int z = g >> 12, b = (g >> 8) & 15;
        const float* X = (z == 0) ? q : (z == 1) ? k : v;
        return X + (size_t)b * CH * HWSZ + (g & 255) * 64;
    };

    float fv[32];
    {   // prologue loads for tile gbase
        const float* xb = xptr(gbase) + pB + (size_t)(cg * 32) * HWSZ;
#pragma unroll
        for (int i = 0; i < 32; ++i) fv[i] = xb[(size_t)i * HWSZ];
    }
#pragma unroll
    for (int i = 0; i < 4; ++i) {   // pack tile 0 -> lB[0]
        uint4 u;
        u.x = pkbf(fv[i*8+0], fv[i*8+1]); u.y = pkbf(fv[i*8+2], fv[i*8+3]);
        u.z = pkbf(fv[i*8+4], fv[i*8+5]); u.w = pkbf(fv[i*8+6], fv[i*8+7]);
        *reinterpret_cast<uint4*>(&lB[0][pB * ROWS + ((cg * 4 + i) ^ psw) * 8]) = u;
    }
    __syncthreads();

    for (int it = 0; it < NITP; ++it) {
        const int g = gbase + it;
        const int z = g >> 12;
        const int b = (g >> 8) & 15;
        const int p0 = (g & 255) * 64;

        // issue next tile's loads (in flight during compute+store)
        if (it + 1 < NITP) {
            const float* xb = xptr(g + 1) + pB + (size_t)(cg * 32) * HWSZ;
#pragma unroll
            for (int i = 0; i < 32; ++i) fv[i] = xb[(size_t)i * HWSZ];
        }

        // compute from lB[it&1]
        const unsigned short* Wb = wb + z * 65536;
        f32x4 acc[2][4];
        const f32x4 zero = {0.f, 0.f, 0.f, 0.f};
#pragma unroll
        for (int m = 0; m < 2; ++m)
#pragma unroll
            for (int n = 0; n < 4; ++n) acc[m][n] = zero;

#pragma unroll
        for (int ks = 0; ks < 8; ++ks) {
            bf16x8 af[2];
#pragma unroll
            for (int m = 0; m < 2; ++m)
                af[m] = *reinterpret_cast<const bf16x8*>(Wb + (wid * 32 + m * 16 + lrow) * 256 + ks * 32 + lkg * 8);
            bf16x8 bfv[4];
#pragma unroll
            for (int n = 0; n < 4; ++n) {
                int row = n * 16 + lrow;
                bfv[n] = *reinterpret_cast<const bf16x8*>(&lB[it & 1][row * ROWS + ((ks * 4 + lkg) ^ (row >> 3)) * 8]);
            }
#pragma unroll
            for (int m = 0; m < 2; ++m)
#pragma unroll
                for (int n = 0; n < 4; ++n)
                    acc[m][n] = __builtin_amdgcn_mfma_f32_16x16x32_bf16(af[m], bfv[n], acc[m][n], 0, 0, 0);
        }

        // store tile (head = wid, f16, pixel-major; z=1,2 padded)
        {
            unsigned short* Y;
            size_t pixstride;
            if (z == 0)      { Y = qh;   pixstride = HWSZ; }
            else if (z == 1) { Y = kpad; pixstride = PPIX; }
            else             { Y = vpad; pixstride = PPIX; }
            Y += (size_t)b * NHEAD * pixstride * DHEAD;
            const int lr = lane >> 4, lc = lane & 15;
#pragma unroll
            for (int m = 0; m < 2; ++m)
#pragma unroll
                for (int n = 0; n < 4; ++n) {
                    int d0 = m * 16 + lr * 4;
                    int p = p0 + n * 16 + lc;
                    ushort4 pk;
                    pk.x = f2h(acc[m][n][0]); pk.y = f2h(acc[m][n][1]);
                    pk.z = f2h(acc[m][n][2]); pk.w = f2h(acc[m][n][3]);
                    size_t pix;
                    if (z == 0) pix = (size_t)wid * HWSZ + p;
                    else { int row = p >> 7, col = p & 127; pix = (size_t)wid * PPIX + (size_t)(row + 2) * PW + (col + 2); }
                    *reinterpret_cast<ushort4*>(&Y[pix * DHEAD + d0]) = pk;
                }
        }

        // pack next tile into the other buffer
        if (it + 1 < NITP) {
#pragma unroll
            for (int i = 0; i < 4; ++i) {
                uint4 u;
                u.x = pkbf(fv[i*8+0], fv[i*8+1]); u.y = pkbf(fv[i*8+2], fv[i*8+3]);
                u.z = pkbf(fv[i*8+4], fv[i*8+5]); u.w = pkbf(fv[i*8+6], fv[i*8+7]);
                *reinterpret_cast<uint4*>(&lB[(it + 1) & 1][pB * ROWS + ((cg * 4 + i) ^ psw) * 8]) = u;
            }
        }
        __syncthreads();
    }
}

// ---------------------------------------------------------------------------
// Kernel 2: local 5x5 attention — 4 lanes per pixel, contiguous 1KB/wave.
// Output converted to BF16 (pixel-major, in place over qh). Unchanged.
// ---------------------------------------------------------------------------
__global__ __launch_bounds__(1024)
void attn_kernel(unsigned short* __restrict__ qh,
                 const unsigned short* __restrict__ kpad,
                 const unsigned short* __restrict__ vpad)
{
    const int t = threadIdx.x;
    const int swz = (blockIdx.x & 7) * 1024 + (blockIdx.x >> 3);
    const int bh = swz >> 6;
    const int tile = swz & 63;
    const int x0 = (tile & 7) * 16, y0 = (tile >> 3) * 16;
    const int qc = t & 3;
    const int px = (t >> 2) & 15;
    const int py = t >> 6;
    const int gx = x0 + px, gy = y0 + py;

    unsigned short* qp = qh + ((size_t)bh * HWSZ + gy * WW + gx) * DHEAD + qc * 8;
    const unsigned short* kb = kpad + (size_t)bh * PPIX * DHEAD + qc * 8;
    const unsigned short* vb = vpad + (size_t)bh * PPIX * DHEAD + qc * 8;

    union { uint4 u; h2v h2[4]; } Q;
    Q.u = *reinterpret_cast<const uint4*>(qp);

    float ew[25];
#pragma unroll
    for (int wy = 0; wy < 5; ++wy) {
        const unsigned short* krow = kb + (size_t)((gy + wy) * PW + gx) * DHEAD;
#pragma unroll
        for (int wx = 0; wx < 5; ++wx) {
            union { uint4 u; h2v h2[4]; } K;
            K.u = *reinterpret_cast<const uint4*>(krow + wx * DHEAD);
            float s = 0.f;
#pragma unroll
            for (int j = 0; j < 4; ++j)
                s = DOT2(Q.h2[j], K.h2[j], s);
            s += __shfl_xor(s, 1);
            s += __shfl_xor(s, 2);
            ew[wy * 5 + wx] = __expf(fmaxf(s, 0.f) * 0.17677669529663687f);
        }
    }

    float sum = 0.f;
#pragma unroll
    for (int i = 0; i < 25; ++i) sum += ew[i];
    const float inv = 1.f / sum;

    union { uint4 u; h2v h2[4]; } A;
    const h2v hz = {(_Float16)0.f, (_Float16)0.f};
#pragma unroll
    for (int j = 0; j < 4; ++j) A.h2[j] = hz;

#pragma unroll
    for (int wy = 0; wy < 5; ++wy) {
        const unsigned short* vrow = vb + (size_t)((gy + wy) * PW + gx) * DHEAD;
#pragma unroll
        for (int wx = 0; wx < 5; ++wx) {
            _Float16 wh = (_Float16)(ew[wy * 5 + wx] * inv);
            h2v w2 = {wh, wh};
            union { uint4 u; h2v h2[4]; } V;
            V.u = *reinterpret_cast<const uint4*>(vrow + wx * DHEAD);
#pragma unroll
            for (int j = 0; j < 4; ++j)
                A.h2[j] += w2 * V.h2[j];
        }
    }

    uint4 o;
    o.x = pkbf((float)A.h2[0][0], (float)A.h2[0][1]);
    o.y = pkbf((float)A.h2[1][0], (float)A.h2[1][1]);
    o.z = pkbf((float)A.h2[2][0], (float)A.h2[2][1]);
    o.w = pkbf((float)A.h2[3][0], (float)A.h2[3][1]);
    *reinterpret_cast<uint4*>(qp) = o;
}

// ---------------------------------------------------------------------------
// Kernel 3: o = wfc @ attn_out + residual, LayerNorm. PERSISTENT, same
// cross-tile double-buffer pattern as proj.
// ---------------------------------------------------------------------------
__global__ __launch_bounds__(512, 4)
void fcln_kernel(const unsigned short* __restrict__ ob, const unsigned short* __restrict__ wfcb,
                 const float* __restrict__ qres, const float* __restrict__ lnw,
                 const float* __restrict__ lnb, float* __restrict__ out)
{
    __shared__ __align__(16) unsigned short lB[2][64 * ROWS];  // 67.6 KB
    __shared__ float lsum[8][64];
    __shared__ float lssq[8][64];

    const int t = threadIdx.x;
    const int lane = t & 63;
    const int wid  = t >> 6;
    const int lrow = lane & 15;
    const int lkg  = lane >> 4;

    const int gbase = blockIdx.x * NITF;

    auto stage_load = [&](int g, uint4* bv) {
        const int b = g >> 8;
        const int p0 = (g & 255) * 64;
#pragma unroll
        for (int r = 0; r < 4; ++r) {
            int idx = r * 512 + t;
            int h = idx >> 8;
            int rem = idx & 255;
            int px = rem >> 2, qc = rem & 3;
            bv[r] = *reinterpret_cast<const uint4*>(
                ob + ((size_t)(b * NHEAD + h) * HWSZ + p0 + px) * DHEAD + qc * 8);
        }
    };
    auto stage_pack = [&](int buf, const uint4* bv) {
#pragma unroll
        for (int r = 0; r < 4; ++r) {
            int idx = r * 512 + t;
            int h = idx >> 8;
            int rem = idx & 255;
            int px = rem >> 2, qc = rem & 3;
            *reinterpret_cast<uint4*>(&lB[buf][px * ROWS + ((h * 4 + qc) ^ (px >> 3)) * 8]) = bv[r];
        }
    };

    uint4 bv[4];
    stage_load(gbase, bv);
    stage_pack(0, bv);
    __syncthreads();

    for (int it = 0; it < NITF; ++it) {
        const int g = gbase + it;
        const int b = g >> 8;
        const int p0 = (g & 255) * 64;

        if (it + 1 < NITF) stage_load(g + 1, bv);

        f32x4 acc[2][4];
        const f32x4 zero = {0.f, 0.f, 0.f, 0.f};
#pragma unroll
        for (int m = 0; m < 2; ++m)
#pragma unroll
            for (int n = 0; n < 4; ++n) acc[m][n] = zero;

#pragma unroll
        for (int ks = 0; ks < 8; ++ks) {
            bf16x8 af[2];
#pragma unroll
            for (int m = 0; m < 2; ++m)
                af[m] = *reinterpret_cast<const bf16x8*>(wfcb + (wid * 32 + m * 16 + lrow) * 256 + ks * 32 + lkg * 8);
            bf16x8 bfv[4];
#pragma unroll
            for (int n = 0; n < 4; ++n) {
                int row = n * 16 + lrow;
                bfv[n] = *reinterpret_cast<const bf16x8*>(&lB[it & 1][row * ROWS + ((ks * 4 + lkg) ^ (row >> 3)) * 8]);
            }
#pragma unroll
            for (int m = 0; m < 2; ++m)
#pragma unroll
                for (int n = 0; n < 4; ++n)
                    acc[m][n] = __builtin_amdgcn_mfma_f32_16x16x32_bf16(af[m], bfv[n], acc[m][n], 0, 0, 0);
        }

        // residual + LN + store
        const int lr = lane >> 4, lc = lane & 15;
        const float* qb = qres + (size_t)b * CH * HWSZ;
#pragma unroll
        for (int m = 0; m < 2; ++m)
#pragma unroll
            for (int n = 0; n < 4; ++n)
#pragma unroll
                for (int j = 0; j < 4; ++j) {
                    int o = wid * 32 + m * 16 + lr * 4 + j;
                    int p = p0 + n * 16 + lc;
                    acc[m][n][j] += qb[(size_t)o * HWSZ + p];
                }

        float s[4], s2[4];
#pragma unroll
        for (int n = 0; n < 4; ++n) {
            float a = 0.f, c2 = 0.f;
#pragma unroll
            for (int m = 0; m < 2; ++m)
#pragma unroll
                for (int j = 0; j < 4; ++j) {
                    float x = acc[m][n][j];
                    a += x; c2 += x * x;
                }
            a  += __shfl_xor(a, 16);  a  += __shfl_xor(a, 32);
            c2 += __shfl_xor(c2, 16); c2 += __shfl_xor(c2, 32);
            s[n] = a; s2[n] = c2;
        }
        if (lane < 16) {
#pragma unroll
            for (int n = 0; n < 4; ++n) {
                lsum[wid][n * 16 + lane] = s[n];
                lssq[wid][n * 16 + lane] = s2[n];
            }
        }
        __syncthreads();

        float mu[4], rs[4];
#pragma unroll
        for (int n = 0; n < 4; ++n) {
            int p = n * 16 + lc;
            float ts = 0.f, tq = 0.f;
#pragma unroll
            for (int w = 0; w < 8; ++w) { ts += lsum[w][p]; tq += lssq[w][p]; }
            float m_ = ts * (1.f / 256.f);
            float v_ = tq * (1.f / 256.f) - m_ * m_;
            mu[n] = m_;
            rs[n] = rsqrtf(v_ + 1e-6f);
        }

        float* op = out + (size_t)b * CH * HWSZ;
#pragma unroll
        for (int m = 0; m < 2; ++m)
#pragma unroll
            for (int j = 0; j < 4; ++j) {
                int o = wid * 32 + m * 16 + lr * 4 + j;
                float g_ = lnw[o], bb = lnb[o];
#pragma unroll
                for (int n = 0; n < 4; ++n) {
                    int p = p0 + n * 16 + lc;
                    op[(size_t)o * HWSZ + p] = (acc[m][n][j] - mu[n]) * rs[n] * g_ + bb;
                }
            }

        if (it + 1 < NITF) stage_pack((it + 1) & 1, bv);
        __syncthreads();
    }
}

extern "C" void kernel_launch(void* const* d_in, const int* in_sizes, int n_in,
                              void* d_out, int out_size, void* d_ws, size_t ws_size,
                              hipStream_t stream) {
    const float* q   = (const float*)d_in[0];
    const float* k   = (const float*)d_in[1];
    const float* v   = (const float*)d_in[2];
    const float* wq  = (const float*)d_in[3];
    const float* wk  = (const float*)d_in[4];
    const float* wv  = (const float*)d_in[5];
    const float* wfc = (const float*)d_in[6];
    const float* lnw = (const float*)d_in[7];
    const float* lnb = (const float*)d_in[8];

    const size_t qsz = (size_t)BATCH * NHEAD * HWSZ * DHEAD;   // 67,108,864
    const size_t psz = (size_t)BATCH * NHEAD * PPIX * DHEAD;   // 71,368,704
    if (ws_size < (qsz + 2 * psz + 4 * 65536) * sizeof(unsigned short)) return;

    unsigned short* qh = (unsigned short*)d_ws;   // q proj (f16), then attn output (bf16, in place)
    unsigned short* kp = qh + qsz;
    unsigned short* vp = kp + psz;
    unsigned short* wb = vp + psz;                // 512KB bf16 weight stash (wq|wk|wv|wfc)

    zpad_kernel<<<256, 256, 0, stream>>>(kp, vp);
    prep_kernel<<<dim3(32, 4), 256, 0, stream>>>(wq, wk, wv, wfc, wb);
    proj_kernel<<<NBLK, 512, 0, stream>>>(q, k, v, wb, qh, kp, vp);
    attn_kernel<<<8192, 1024, 0, stream>>>(qh, kp, vp);
    fcln_kernel<<<NBLK, 512, 0, stream>>>(qh, wb + 3 * 65536, q, lnw, lnb, (float*)d_out);
}

// Round 13
// 724.972 us; speedup vs baseline: 1.5645x; 1.5645x over previous
//
#include <hip/hip_runtime.h>
#include <hip/hip_bf16.h>

#define BATCH 16
#define CH 256
#define HH 128
#define WW 128
#define HWSZ (HH * WW)
#define NHEAD 8
#define DHEAD 32
#define PW 132       // padded spatial width  (2 halo each side)
#define PPIX (132 * 132)
#define ROWS 264     // lB row stride in shorts
#define ASTR 40      // lA row stride in shorts (32ch + pad)

typedef __attribute__((ext_vector_type(8))) short bf16x8;
typedef __attribute__((ext_vector_type(4))) float f32x4;
typedef _Float16 h2v __attribute__((ext_vector_type(2)));

__device__ __forceinline__ unsigned short f2h(float f) {
    _Float16 h = (_Float16)f;
    return __builtin_bit_cast(unsigned short, h);
}
// packed f32x2 -> bf16x2 in one u32 (v_cvt_pk_bf16_f32 on gfx950)
__device__ __forceinline__ unsigned pkbf(float a, float b) {
    __hip_bfloat162_raw r = __hip_bfloat162_raw(__float22bfloat162_rn(make_float2(a, b)));
    return (unsigned)r.x | ((unsigned)r.y << 16);
}

#if __has_builtin(__builtin_amdgcn_fdot2)
#define DOT2(a, b, c) __builtin_amdgcn_fdot2((a), (b), (c), false)
#else
#define DOT2(a, b, c) ((c) + (float)(a)[0] * (float)(b)[0] + (float)(a)[1] * (float)(b)[1])
#endif

// ---------------------------------------------------------------------------
// Kernel Z: zero the spatial border of padded K/V buffers (1040 px per b,h).
// ---------------------------------------------------------------------------
__global__ __launch_bounds__(256)
void zpad_kernel(unsigned short* __restrict__ kpad, unsigned short* __restrict__ vpad)
{
    int bid = blockIdx.x;  // 0..255 : (bh, tensor)
    unsigned short* dst = ((bid & 1) ? vpad : kpad) + (size_t)(bid >> 1) * PPIX * DHEAD;
    const uint4 z = {0u, 0u, 0u, 0u};
    for (int i = threadIdx.x; i < 1040; i += 256) {
        int row, col;
        if (i < 264)      { row = i / 132; col = i - row * 132; }
        else if (i < 528) { int j = i - 264; int r = j / 132; row = 130 + r; col = j - r * 132; }
        else              { int j = i - 528; row = 2 + (j >> 2); int c = j & 3; col = (c < 2) ? c : (128 + c); }
        uint4* p = reinterpret_cast<uint4*>(dst + (size_t)(row * PW + col) * DHEAD);
        p[0] = z; p[1] = z; p[2] = z; p[3] = z;
    }
}

// ---------------------------------------------------------------------------
// Kernel 0: convert wq|wk|wv|wfc fp32 -> bf16, stashed in d_ws tail.
// ---------------------------------------------------------------------------
__global__ __launch_bounds__(256)
void prep_kernel(const float* __restrict__ wq, const float* __restrict__ wk,
                 const float* __restrict__ wv, const float* __restrict__ wfc,
                 unsigned short* __restrict__ wb)
{
    const float* src = (blockIdx.y == 0) ? wq : (blockIdx.y == 1) ? wk
                     : (blockIdx.y == 2) ? wv : wfc;
    unsigned short* dst = wb + blockIdx.y * 65536;
    int e = (blockIdx.x * 256 + threadIdx.x) * 8;
    const float4* s = reinterpret_cast<const float4*>(src + e);
    float4 a = s[0], c = s[1];
    uint4 u;
    u.x = pkbf(a.x, a.y); u.y = pkbf(a.z, a.w);
    u.z = pkbf(c.x, c.y); u.w = pkbf(c.z, c.w);
    *reinterpret_cast<uint4*>(dst + e) = u;
}

// ---------------------------------------------------------------------------
// Kernel 1: projections -> f16, pixel-major. BM=256, BN=64, 512 threads.
// lB: full 64px x 256ch panel staged ONCE via float4 (4px/lane) loads.
// lA: per-ks W tile, double-buffered, T14-ordered (glb->reg early,
// ds_write late, after MFMA) so in-loop vmcnt never drains prematurely.
// ---------------------------------------------------------------------------
__global__ __launch_bounds__(512)
void proj_kernel(const float* __restrict__ q, const float* __restrict__ k,
                 const float* __restrict__ v, const unsigned short* __restrict__ wb,
                 unsigned short* __restrict__ qh, unsigned short* __restrict__ kpad,
                 unsigned short* __restrict__ vpad)
{
    __shared__ __align__(16) unsigned short lB[64 * ROWS];     // 33 KB
    __shared__ __align__(16) unsigned short lA[2][256 * ASTR]; // 40 KB

    const int t = threadIdx.x;
    const int b = blockIdx.y;
    const int p0 = blockIdx.x * 64;
    const int z = blockIdx.z;

    const float* X; unsigned short* Y;
    if (z == 0)      { X = q; Y = qh; }
    else if (z == 1) { X = k; Y = kpad; }
    else             { X = v; Y = vpad; }
    const unsigned short* Wb = wb + z * 65536;
    X += (size_t)b * CH * HWSZ;
    const size_t pixstride = (z == 0) ? (size_t)HWSZ : (size_t)PPIX;
    Y += (size_t)b * NHEAD * pixstride * DHEAD;

    const int lane = t & 63;
    const int wid  = t >> 6;   // 0..7 : 32-out-ch slab
    const int lrow = lane & 15;
    const int lkg  = lane >> 4;
    // lB staging map: 4 px per lane, 8 channels
    const int pxq  = t & 15;
    const int oct  = t >> 4;   // 0..31 channel octet
    // lA staging map: 2 x uint4 per thread
    const int ao0 = t >> 1,       ak0 = (t & 1) * 2;      // row, chunk(2x)
    // (each thread covers row ao0, chunks ak0, ak0+1)

    // ---- stage lB: 8 float4 loads (1KB-contiguous per wave-instr) ----
    {
        const float* xb = X + p0 + pxq * 4 + (size_t)(oct * 8) * HWSZ;
        float4 f0 = *reinterpret_cast<const float4*>(xb + 0 * HWSZ);
        float4 f1 = *reinterpret_cast<const float4*>(xb + 1 * HWSZ);
        float4 f2 = *reinterpret_cast<const float4*>(xb + 2 * HWSZ);
        float4 f3 = *reinterpret_cast<const float4*>(xb + 3 * HWSZ);
        float4 f4 = *reinterpret_cast<const float4*>(xb + 4 * HWSZ);
        float4 f5 = *reinterpret_cast<const float4*>(xb + 5 * HWSZ);
        float4 f6 = *reinterpret_cast<const float4*>(xb + 6 * HWSZ);
        float4 f7 = *reinterpret_cast<const float4*>(xb + 7 * HWSZ);
        uint4 u;
#define PACKJ(J, C) \
        u.x = pkbf(f0.C, f1.C); u.y = pkbf(f2.C, f3.C); \
        u.z = pkbf(f4.C, f5.C); u.w = pkbf(f6.C, f7.C); \
        *reinterpret_cast<uint4*>(&lB[(pxq * 4 + J) * ROWS + oct * 8]) = u;
        PACKJ(0, x) PACKJ(1, y) PACKJ(2, z) PACKJ(3, w)
#undef PACKJ
    }
    // ---- stage lA[0] directly ----
    {
        uint4 w0 = *reinterpret_cast<const uint4*>(Wb + ao0 * 256 + ak0 * 8);
        uint4 w1 = *reinterpret_cast<const uint4*>(Wb + ao0 * 256 + ak0 * 8 + 8);
        *reinterpret_cast<uint4*>(&lA[0][ao0 * ASTR + ak0 * 8]) = w0;
        *reinterpret_cast<uint4*>(&lA[0][ao0 * ASTR + ak0 * 8 + 8]) = w1;
    }

    f32x4 acc[2][4];
    const f32x4 zero = {0.f, 0.f, 0.f, 0.f};
#pragma unroll
    for (int m = 0; m < 2; ++m)
#pragma unroll
        for (int n = 0; n < 4; ++n) acc[m][n] = zero;

    __syncthreads();

#pragma unroll
    for (int ks = 0; ks < 8; ++ks) {
        // (1) issue next-A global loads early (W is L2-hot)
        uint4 w0, w1;
        if (ks < 7) {
            w0 = *reinterpret_cast<const uint4*>(Wb + ao0 * 256 + (ks + 1) * 32 + ak0 * 8);
            w1 = *reinterpret_cast<const uint4*>(Wb + ao0 * 256 + (ks + 1) * 32 + ak0 * 8 + 8);
        }
        // (2) ds_read fragments
        bf16x8 af[2], bfv[4];
#pragma unroll
        for (int m = 0; m < 2; ++m)
            af[m] = *reinterpret_cast<const bf16x8*>(&lA[ks & 1][(wid * 32 + m * 16 + lrow) * ASTR + lkg * 8]);
#pragma unroll
        for (int n = 0; n < 4; ++n)
            bfv[n] = *reinterpret_cast<const bf16x8*>(&lB[(n * 16 + lrow) * ROWS + (ks * 4 + lkg) * 8]);
        // (3) MFMA
#pragma unroll
        for (int m = 0; m < 2; ++m)
#pragma unroll
            for (int n = 0; n < 4; ++n)
                acc[m][n] = __builtin_amdgcn_mfma_f32_16x16x32_bf16(af[m], bfv[n], acc[m][n], 0, 0, 0);
        // (4) ds_write next-A (vmcnt wait hidden under (2)(3)), (5) barrier
        if (ks < 7) {
            *reinterpret_cast<uint4*>(&lA[(ks + 1) & 1][ao0 * ASTR + ak0 * 8]) = w0;
            *reinterpret_cast<uint4*>(&lA[(ks + 1) & 1][ao0 * ASTR + ak0 * 8 + 8]) = w1;
            __syncthreads();
        }
    }

    const int lr = lane >> 4, lc = lane & 15;
#pragma unroll
    for (int m = 0; m < 2; ++m)
#pragma unroll
        for (int n = 0; n < 4; ++n) {
            int d0 = m * 16 + lr * 4;            // head = wid
            int p = p0 + n * 16 + lc;
            ushort4 pk;
            pk.x = f2h(acc[m][n][0]); pk.y = f2h(acc[m][n][1]);
            pk.z = f2h(acc[m][n][2]); pk.w = f2h(acc[m][n][3]);
            size_t pix;
            if (z == 0) pix = (size_t)wid * HWSZ + p;
            else { int row = p >> 7, col = p & 127; pix = (size_t)wid * PPIX + (size_t)(row + 2) * PW + (col + 2); }
            *reinterpret_cast<ushort4*>(&Y[pix * DHEAD + d0]) = pk;
        }
}

// ---------------------------------------------------------------------------
// Kernel 2: local 5x5 attention — 4 lanes per pixel, contiguous 1KB/wave.
// Output converted to BF16 (pixel-major, in place over qh). R11-proven.
// ---------------------------------------------------------------------------
__global__ __launch_bounds__(1024)
void attn_kernel(unsigned short* __restrict__ qh,
                 const unsigned short* __restrict__ kpad,
                 const unsigned short* __restrict__ vpad)
{
    const int t = threadIdx.x;
    const int swz = (blockIdx.x & 7) * 1024 + (blockIdx.x >> 3);
    const int bh = swz >> 6;
    const int tile = swz & 63;
    const int x0 = (tile & 7) * 16, y0 = (tile >> 3) * 16;
    const int qc = t & 3;
    const int px = (t >> 2) & 15;
    const int py = t >> 6;
    const int gx = x0 + px, gy = y0 + py;

    unsigned short* qp = qh + ((size_t)bh * HWSZ + gy * WW + gx) * DHEAD + qc * 8;
    const unsigned short* kb = kpad + (size_t)bh * PPIX * DHEAD + qc * 8;
    const unsigned short* vb = vpad + (size_t)bh * PPIX * DHEAD + qc * 8;

    union { uint4 u; h2v h2[4]; } Q;
    Q.u = *reinterpret_cast<const uint4*>(qp);

    float ew[25];
#pragma unroll
    for (int wy = 0; wy < 5; ++wy) {
        const unsigned short* krow = kb + (size_t)((gy + wy) * PW + gx) * DHEAD;
#pragma unroll
        for (int wx = 0; wx < 5; ++wx) {
            union { uint4 u; h2v h2[4]; } K;
            K.u = *reinterpret_cast<const uint4*>(krow + wx * DHEAD);
            float s = 0.f;
#pragma unroll
            for (int j = 0; j < 4; ++j)
                s = DOT2(Q.h2[j], K.h2[j], s);
            s += __shfl_xor(s, 1);
            s += __shfl_xor(s, 2);
            ew[wy * 5 + wx] = __expf(fmaxf(s, 0.f) * 0.17677669529663687f);
        }
    }

    float sum = 0.f;
#pragma unroll
    for (int i = 0; i < 25; ++i) sum += ew[i];
    const float inv = 1.f / sum;

    union { uint4 u; h2v h2[4]; } A;
    const h2v hz = {(_Float16)0.f, (_Float16)0.f};
#pragma unroll
    for (int j = 0; j < 4; ++j) A.h2[j] = hz;

#pragma unroll
    for (int wy = 0; wy < 5; ++wy) {
        const unsigned short* vrow = vb + (size_t)((gy + wy) * PW + gx) * DHEAD;
#pragma unroll
        for (int wx = 0; wx < 5; ++wx) {
            _Float16 wh = (_Float16)(ew[wy * 5 + wx] * inv);
            h2v w2 = {wh, wh};
            union { uint4 u; h2v h2[4]; } V;
            V.u = *reinterpret_cast<const uint4*>(vrow + wx * DHEAD);
#pragma unroll
            for (int j = 0; j < 4; ++j)
                A.h2[j] += w2 * V.h2[j];
        }
    }

    uint4 o;
    o.x = pkbf((float)A.h2[0][0], (float)A.h2[0][1]);
    o.y = pkbf((float)A.h2[1][0], (float)A.h2[1][1]);
    o.z = pkbf((float)A.h2[2][0], (float)A.h2[2][1]);
    o.w = pkbf((float)A.h2[3][0], (float)A.h2[3][1]);
    *reinterpret_cast<uint4*>(qp) = o;
}

// ---------------------------------------------------------------------------
// Kernel 3: o = wfc @ attn_out + residual, LayerNorm. Same lA/lB scheme as
// proj; lB stage is pure uint4 copies (bf16 pixel-major, contiguous 1KB/wave).
// ---------------------------------------------------------------------------
__global__ __launch_bounds__(512)
void fcln_kernel(const unsigned short* __restrict__ ob, const unsigned short* __restrict__ wfcb,
                 const float* __restrict__ qres, const float* __restrict__ lnw,
                 const float* __restrict__ lnb, float* __restrict__ out)
{
    __shared__ __align__(16) unsigned short lB[64 * ROWS];     // 33 KB
    __shared__ __align__(16) unsigned short lA[2][256 * ASTR]; // 40 KB
    __shared__ float lsum[8][64];
    __shared__ float lssq[8][64];

    const int t = threadIdx.x;
    const int b = blockIdx.y;
    const int p0 = blockIdx.x * 64;

    const int lane = t & 63;
    const int wid  = t >> 6;
    const int lrow = lane & 15;
    const int lkg  = lane >> 4;
    const int ao0 = t >> 1, ak0 = (t & 1) * 2;

    // ---- stage lB: 4 x uint4 per thread (contiguous 1KB per wave-instr) ----
#pragma unroll
    for (int r = 0; r < 4; ++r) {
        int idx = r * 512 + t;
        int h = idx >> 8;
        int rem = idx & 255;
        int px = rem >> 2, qc = rem & 3;
        uint4 bv = *reinterpret_cast<const uint4*>(
            ob + ((size_t)(b * NHEAD + h) * HWSZ + p0 + px) * DHEAD + qc * 8);
        *reinterpret_cast<uint4*>(&lB[px * ROWS + (h * 4 + qc) * 8]) = bv;
    }
    // ---- stage lA[0] ----
    {
        uint4 w0 = *reinterpret_cast<const uint4*>(wfcb + ao0 * 256 + ak0 * 8);
        uint4 w1 = *reinterpret_cast<const uint4*>(wfcb + ao0 * 256 + ak0 * 8 + 8);
        *reinterpret_cast<uint4*>(&lA[0][ao0 * ASTR + ak0 * 8]) = w0;
        *reinterpret_cast<uint4*>(&lA[0][ao0 * ASTR + ak0 * 8 + 8]) = w1;
    }

    f32x4 acc[2][4];
    const f32x4 zero = {0.f, 0.f, 0.f, 0.f};
#pragma unroll
    for (int m = 0; m < 2; ++m)
#pragma unroll
        for (int n = 0; n < 4; ++n) acc[m][n] = zero;

    __syncthreads();

#pragma unroll
    for (int ks = 0; ks < 8; ++ks) {
        uint4 w0, w1;
        if (ks < 7) {
            w0 = *reinterpret_cast<const uint4*>(wfcb + ao0 * 256 + (ks + 1) * 32 + ak0 * 8);
            w1 = *reinterpret_cast<const uint4*>(wfcb + ao0 * 256 + (ks + 1) * 32 + ak0 * 8 + 8);
        }
        bf16x8 af[2], bfv[4];
#pragma unroll
        for (int m = 0; m < 2; ++m)
            af[m] = *reinterpret_cast<const bf16x8*>(&lA[ks & 1][(wid * 32 + m * 16 + lrow) * ASTR + lkg * 8]);
#pragma unroll
        for (int n = 0; n < 4; ++n)
            bfv[n] = *reinterpret_cast<const bf16x8*>(&lB[(n * 16 + lrow) * ROWS + (ks * 4 + lkg) * 8]);
#pragma unroll
        for (int m = 0; m < 2; ++m)
#pragma unroll
            for (int n = 0; n < 4; ++n)
                acc[m][n] = __builtin_amdgcn_mfma_f32_16x16x32_bf16(af[m], bfv[n], acc[m][n], 0, 0, 0);
        if (ks < 7) {
            *reinterpret_cast<uint4*>(&lA[(ks + 1) & 1][ao0 * ASTR + ak0 * 8]) = w0;
            *reinterpret_cast<uint4*>(&lA[(ks + 1) & 1][ao0 * ASTR + ak0 * 8 + 8]) = w1;
            __syncthreads();
        }
    }

    const int lr = lane >> 4, lc = lane & 15;
    const float* qb = qres + (size_t)b * CH * HWSZ;
#pragma unroll
    for (int m = 0; m < 2; ++m)
#pragma unroll
        for (int n = 0; n < 4; ++n)
#pragma unroll
            for (int j = 0; j < 4; ++j) {
                int o = wid * 32 + m * 16 + lr * 4 + j;
                int p = p0 + n * 16 + lc;
                acc[m][n][j] += qb[(size_t)o * HWSZ + p];
            }

    float s[4], s2[4];
#pragma unroll
    for (int n = 0; n < 4; ++n) {
        float a = 0.f, c2 = 0.f;
#pragma unroll
        for (int m = 0; m < 2; ++m)
#pragma unroll
            for (int j = 0; j < 4; ++j) {
                float x = acc[m][n][j];
                a += x; c2 += x * x;
            }
        a  += __shfl_xor(a, 16);  a  += __shfl_xor(a, 32);
        c2 += __shfl_xor(c2, 16); c2 += __shfl_xor(c2, 32);
        s[n] = a; s2[n] = c2;
    }
    __syncthreads();
    if (lane < 16) {
#pragma unroll
        for (int n = 0; n < 4; ++n) {
            lsum[wid][n * 16 + lane] = s[n];
            lssq[wid][n * 16 + lane] = s2[n];
        }
    }
    __syncthreads();

    float mu[4], rs[4];
#pragma unroll
    for (int n = 0; n < 4; ++n) {
        int p = n * 16 + lc;
        float ts = 0.f, tq = 0.f;
#pragma unroll
        for (int w = 0; w < 8; ++w) { ts += lsum[w][p]; tq += lssq[w][p]; }
        float m_ = ts * (1.f / 256.f);
        float v_ = tq * (1.f / 256.f) - m_ * m_;
        mu[n] = m_;
        rs[n] = rsqrtf(v_ + 1e-6f);
    }

    float* op = out + (size_t)b * CH * HWSZ;
#pragma unroll
    for (int m = 0; m < 2; ++m)
#pragma unroll
        for (int j = 0; j < 4; ++j) {
            int o = wid * 32 + m * 16 + lr * 4 + j;
            float g = lnw[o], bb = lnb[o];
#pragma unroll
            for (int n = 0; n < 4; ++n) {
                int p = p0 + n * 16 + lc;
                op[(size_t)o * HWSZ + p] = (acc[m][n][j] - mu[n]) * rs[n] * g + bb;
            }
        }
}

extern "C" void kernel_launch(void* const* d_in, const int* in_sizes, int n_in,
                              void* d_out, int out_size, void* d_ws, size_t ws_size,
                              hipStream_t stream) {
    const float* q   = (const float*)d_in[0];
    const float* k   = (const float*)d_in[1];
    const float* v   = (const float*)d_in[2];
    const float* wq  = (const float*)d_in[3];
    const float* wk  = (const float*)d_in[4];
    const float* wv  = (const float*)d_in[5];
    const float* wfc = (const float*)d_in[6];
    const float* lnw = (const float*)d_in[7];
    const float* lnb = (const float*)d_in[8];

    const size_t qsz = (size_t)BATCH * NHEAD * HWSZ * DHEAD;   // 67,108,864
    const size_t psz = (size_t)BATCH * NHEAD * PPIX * DHEAD;   // 71,368,704
    if (ws_size < (qsz + 2 * psz + 4 * 65536) * sizeof(unsigned short)) return;

    unsigned short* qh = (unsigned short*)d_ws;   // q proj (f16), then attn output (bf16, in place)
    unsigned short* kp = qh + qsz;
    unsigned short* vp = kp + psz;
    unsigned short* wb = vp + psz;                // 512KB bf16 weight stash (wq|wk|wv|wfc)

    zpad_kernel<<<256, 256, 0, stream>>>(kp, vp);
    prep_kernel<<<dim3(32, 4), 256, 0, stream>>>(wq, wk, wv, wfc, wb);
    proj_kernel<<<dim3(HWSZ / 64, BATCH, 3), 512, 0, stream>>>(q, k, v, wb, qh, kp, vp);
    attn_kernel<<<8192, 1024, 0, stream>>>(qh, kp, vp);
    fcln_kernel<<<dim3(HWSZ / 64, BATCH), 512, 0, stream>>>(qh, wb + 3 * 65536, q, lnw, lnb, (float*)d_out);
}